// Round 3
// baseline (276.610 us; speedup 1.0000x reference)
//
#include <hip/hip_runtime.h>

// out[v,g,u,d] = W[GE[v,g] % 3, d] + b[d], out shape [V=512, G=4, V=512, D=64] fp32.
// Pure write-BW bound: 256 MiB of stores, ~8 KB of reads.
//
// v3 theory: v2 (linear fill-shaped sweep) == v1 (per-block chunks) == ~2.8 TB/s,
// while rocclr fillBuffer sustains 6.6 TB/s on the same buffer. Pattern-independent
// 2.3x gap => write-allocation in L2/MALL (output is exactly 256 MiB = Infinity
// Cache size => guaranteed full dirty-eviction churn / RFO traffic, ~2x HBM bytes).
// Fix: nontemporal (streaming) stores -> global_store_dwordx4 nt, bypassing
// cache allocation, matching what the runtime's fill kernel does.
//
// v3b: __builtin_nontemporal_store needs a native clang vector type, not
// HIP_vector_type — use ext_vector_type(4) float.
//
// Index math (all exact, no bounds checks needed):
//   i  = bid*256 + tid + k*524288      (float4 index, k = 0..31)
//   d4 = i & 15  == tid & 15           (stride and block base are mult. of 16)
//   vg = i >> 13 == (bid >> 5) + 64*k  (block-uniform -> scalar load of GE)

#define V 512
#define G 4
#define D 64
#define D4 (D / 4)          // 16 float4 per D-row
#define NBLK 2048
#define NTHR 256
#define SWEEP ((size_t)NBLK * NTHR)   // 524288 float4 per sweep (8 MiB)
#define NITER 32                      // 2048*512*16 / 524288

typedef float f32x4 __attribute__((ext_vector_type(4)));

__global__ __launch_bounds__(NTHR) void gembed_kernel(
    const int* __restrict__ GE,      // [V*G] int32, values in [0,3)
    const float* __restrict__ W,     // [3, D]
    const float* __restrict__ b,     // [D]
    float* __restrict__ out)         // [V*G*V*D]
{
    const int bid = blockIdx.x;
    const int tid = threadIdx.x;
    const int d4  = tid & (D4 - 1);

    const f32x4* __restrict__ W4 = (const f32x4*)W;  // [3 * D4]
    const f32x4* __restrict__ b4 = (const f32x4*)b;  // [D4]

    // Precompute the three candidate row-values for this thread's d4 slot.
    const f32x4 bb = b4[d4];
    const f32x4 v0 = W4[0 * D4 + d4] + bb;
    const f32x4 v1 = W4[1 * D4 + d4] + bb;
    const f32x4 v2 = W4[2 * D4 + d4] + bb;

    // Linear sweep: identical store-address shape to fillBuffer.
    f32x4* __restrict__ p = (f32x4*)out + ((size_t)bid * NTHR + tid);
    int vg = bid >> 5;   // block-uniform; advances by 64 per sweep

    #pragma unroll 8
    for (int k = 0; k < NITER; ++k) {
        const int e = GE[vg];        // wave-uniform -> scalar load, L2-resident
        f32x4 v;
        v.x = (e == 0) ? v0.x : ((e == 1) ? v1.x : v2.x);
        v.y = (e == 0) ? v0.y : ((e == 1) ? v1.y : v2.y);
        v.z = (e == 0) ? v0.z : ((e == 1) ? v1.z : v2.z);
        v.w = (e == 0) ? v0.w : ((e == 1) ? v1.w : v2.w);
        __builtin_nontemporal_store(v, p);   // global_store_dwordx4 ... nt
        p  += SWEEP;
        vg += 64;
    }
}

extern "C" void kernel_launch(void* const* d_in, const int* in_sizes, int n_in,
                              void* d_out, int out_size, void* d_ws, size_t ws_size,
                              hipStream_t stream) {
    const int*   GE = (const int*)d_in[0];
    const float* W  = (const float*)d_in[1];
    const float* b  = (const float*)d_in[2];
    float* out = (float*)d_out;

    gembed_kernel<<<NBLK, NTHR, 0, stream>>>(GE, W, b, out);
}